// Round 9
// baseline (170.089 us; speedup 1.0000x reference)
//
#include <hip/hip_runtime.h>

// ---------------------------------------------------------------------------
//   x: (32, 512, 128) fp32 -> rows r = b*128 + c, 4096 rows
//   h[r][n2] = sum_l xt[r][l] * W2[n2][l] + b2[n2],  W2 = lin2_w @ lin1_w
//   out[r][t] = h[r][t] + mamba1(h[r][:])[t]        (x1 branch is exactly 0)
// 3 dispatches: w2t (W2T + b2) -> gemm_h (split-K4, bias in kz0) -> mamba.
// ---------------------------------------------------------------------------

__device__ __forceinline__ float rcp_f(float x) { return __builtin_amdgcn_rcpf(x); }
__device__ __forceinline__ float silu_f(float x) {
    return x * rcp_f(1.0f + __expf(-x));
}
__device__ __forceinline__ float softplus_f(float x) {
    return fmaxf(x, 0.0f) + __logf(1.0f + __expf(-fabsf(x)));
}

// DPP row_shr add (rows of 16 lanes); bound_ctrl=1 -> out-of-row reads 0.
#define DPP_ADD(s, ctrl)                                                       \
    (s) += __int_as_float(__builtin_amdgcn_update_dpp(                         \
        0, __float_as_int(s), (ctrl), 0xf, 0xf, true))

// ---------------------------------------------------------------------------
// Kernel 1: W2T[l*256+n2] = sum_n1 lin2[n2][n1]*lin1[n1][l]  (blocks 0..127)
//           b2 = lin2_w@lin1_b + lin2_b                      (blocks 128..135)
// ---------------------------------------------------------------------------
__global__ __launch_bounds__(256)
void w2t_full(const float* __restrict__ lin2_w, const float* __restrict__ lin1_w,
              const float* __restrict__ lin1_b, const float* __restrict__ lin2_b,
              float* __restrict__ W2T, float* __restrict__ b2) {
    __shared__ float As[64][34];
    __shared__ float Bs[64][36];
    const int bid = blockIdx.x;
    const int tid = threadIdx.x;
    if (bid >= 128) {
        __shared__ float red[8][33];
        const int np = tid & 31;
        const int ks = tid >> 5;
        const int n = (bid - 128) * 32 + np;
        float acc = 0.f;
#pragma unroll 16
        for (int k = ks * 64; k < ks * 64 + 64; k += 4) {
            float4 w  = *(const float4*)&lin2_w[n * 512 + k];
            float4 bb = *(const float4*)&lin1_b[k];
            acc += w.x * bb.x + w.y * bb.y + w.z * bb.z + w.w * bb.w;
        }
        red[ks][np] = acc;
        __syncthreads();
        if (ks == 0) {
            float s = red[0][np] + red[1][np] + red[2][np] + red[3][np] +
                      red[4][np] + red[5][np] + red[6][np] + red[7][np];
            b2[n] = s + lin2_b[n];
        }
        return;
    }
    const int m0 = (bid & 7) * 32;           // n2 tile
    const int n0 = ((bid >> 3) & 15) * 32;   // l tile
    const int tr = tid & 15;
    const int tc = tid >> 4;
    const int ma  = tid >> 3;
    const int kqa = tid & 7;
    const int kb  = tid >> 2;
    const int nqb = tid & 3;
    float acc00 = 0.f, acc01 = 0.f, acc10 = 0.f, acc11 = 0.f;

    for (int k0 = 0; k0 < 512; k0 += 64) {
        float4 a0 = *(const float4*)&lin2_w[(m0 + ma) * 512 + k0 + kqa * 8];
        float4 a1 = *(const float4*)&lin2_w[(m0 + ma) * 512 + k0 + kqa * 8 + 4];
        As[kqa * 8 + 0][ma] = a0.x;
        As[kqa * 8 + 1][ma] = a0.y;
        As[kqa * 8 + 2][ma] = a0.z;
        As[kqa * 8 + 3][ma] = a0.w;
        As[kqa * 8 + 4][ma] = a1.x;
        As[kqa * 8 + 5][ma] = a1.y;
        As[kqa * 8 + 6][ma] = a1.z;
        As[kqa * 8 + 7][ma] = a1.w;
        float4 b0 = *(const float4*)&lin1_w[(k0 + kb) * 512 + n0 + nqb * 8];
        float4 b1 = *(const float4*)&lin1_w[(k0 + kb) * 512 + n0 + nqb * 8 + 4];
        *(float4*)&Bs[kb][nqb * 8]     = b0;
        *(float4*)&Bs[kb][nqb * 8 + 4] = b1;
        __syncthreads();
#pragma unroll 16
        for (int kk = 0; kk < 64; ++kk) {
            float2 av = *(const float2*)&As[kk][tr * 2];
            float2 bv = *(const float2*)&Bs[kk][tc * 2];
            acc00 = fmaf(av.x, bv.x, acc00);
            acc01 = fmaf(av.x, bv.y, acc01);
            acc10 = fmaf(av.y, bv.x, acc10);
            acc11 = fmaf(av.y, bv.y, acc11);
        }
        __syncthreads();
    }
    const int m = m0 + tr * 2;
    const int nn = n0 + tc * 2;
    W2T[nn * 256 + m]           = acc00;
    W2T[nn * 256 + m + 1]       = acc10;
    W2T[(nn + 1) * 256 + m]     = acc01;
    W2T[(nn + 1) * 256 + m + 1] = acc11;
}

// ---------------------------------------------------------------------------
// Kernel 2: hpart[kz][r][n2] = sum_{l in kz*128..+128} xt[r][l]*W2T[l][n2]
// (+ b2 folded into kz==0).  BM=128 (one batch), BN=64, BK=32, 8x4 micro:
// A-rows {tr*4..+3, 64+tr*4..+3} (both tr*4 patterns -> conflict-free),
// B-cols tc*4 (broadcast).  Double-buffered.  grid (32,4,4) = 512 blocks.
// ---------------------------------------------------------------------------
__global__ __launch_bounds__(256)
void gemm_h(const float* __restrict__ x, const float* __restrict__ W2T,
            const float* __restrict__ b2, float* __restrict__ hpart) {
    __shared__ float As[2][32][132];  // [buf][k][r'] 33.8 KB
    __shared__ float Bs[2][32][68];   // [buf][k][n'] 17.4 KB
    const int tid = threadIdx.x;
    const int b  = blockIdx.x;        // batch = M tile of 128 rows
    const int n0 = blockIdx.y * 64;   // n2 tile
    const int kz = blockIdx.z;        // l-chunk of 128
    const int lbase = kz * 128;
    const int r0 = b * 128;
    // A staging: thread (ka=tid>>3, c8=tid&7): 4 float4 from row ka
    const int ka = tid >> 3;
    const int c8 = tid & 7;
    // B staging: thread (kb=tid>>3, n8=tid&7): 2 float4 from row kb
    const int tr = tid & 15;  // A octet (rows tr*4 and 64+tr*4)
    const int tc = tid >> 4;  // B quad
    float acc[8][4] = {{0.f}};

    const float* xp = x + b * 65536;          // x[b][l][c], row stride 128
    const float* wp = W2T + n0;               // row stride 256

    float4 pa0, pa1, pa2, pa3, pb0, pb1;
#define LOADC(l0)                                                              \
    do {                                                                       \
        const float* xr = xp + ((l0) + ka) * 128;                              \
        pa0 = *(const float4*)&xr[c8 * 4];                                     \
        pa1 = *(const float4*)&xr[c8 * 4 + 32];                                \
        pa2 = *(const float4*)&xr[c8 * 4 + 64];                                \
        pa3 = *(const float4*)&xr[c8 * 4 + 96];                                \
        const float* wr = wp + ((l0) + ka) * 256;                              \
        pb0 = *(const float4*)&wr[c8 * 4];                                     \
        pb1 = *(const float4*)&wr[c8 * 4 + 32];                                \
    } while (0)
#define STOREC(buf)                                                            \
    do {                                                                       \
        *(float4*)&As[buf][ka][c8 * 4]      = pa0;                             \
        *(float4*)&As[buf][ka][c8 * 4 + 32] = pa1;                             \
        *(float4*)&As[buf][ka][c8 * 4 + 64] = pa2;                             \
        *(float4*)&As[buf][ka][c8 * 4 + 96] = pa3;                             \
        *(float4*)&Bs[buf][ka][c8 * 4]      = pb0;                             \
        *(float4*)&Bs[buf][ka][c8 * 4 + 32] = pb1;                             \
    } while (0)

    LOADC(lbase);
    STOREC(0);
    for (int c = 0; c < 4; ++c) {
        __syncthreads();
        const int cur = c & 1;
        if (c < 3) LOADC(lbase + (c + 1) * 32);
#pragma unroll
        for (int kk = 0; kk < 32; ++kk) {
            float4 av0 = *(const float4*)&As[cur][kk][tr * 4];
            float4 av1 = *(const float4*)&As[cur][kk][64 + tr * 4];
            float4 bv  = *(const float4*)&Bs[cur][kk][tc * 4];
            const float am[8] = {av0.x, av0.y, av0.z, av0.w,
                                 av1.x, av1.y, av1.z, av1.w};
#pragma unroll
            for (int i = 0; i < 8; ++i) {
                acc[i][0] = fmaf(am[i], bv.x, acc[i][0]);
                acc[i][1] = fmaf(am[i], bv.y, acc[i][1]);
                acc[i][2] = fmaf(am[i], bv.z, acc[i][2]);
                acc[i][3] = fmaf(am[i], bv.w, acc[i][3]);
            }
        }
        if (c < 3) STOREC(cur ^ 1);
    }
#undef LOADC
#undef STOREC
    float4 bias = make_float4(0.f, 0.f, 0.f, 0.f);
    if (kz == 0) bias = *(const float4*)&b2[n0 + tc * 4];
    float* dst = hpart + kz * 1048576;
#pragma unroll
    for (int i = 0; i < 8; ++i) {
        const int rr = r0 + ((i < 4) ? (tr * 4 + i) : (64 + tr * 4 + i - 4));
        float4 v = make_float4(acc[i][0] + bias.x, acc[i][1] + bias.y,
                               acc[i][2] + bias.z, acc[i][3] + bias.w);
        *(float4*)&dst[rr * 256 + n0 + tc * 4] = v;
    }
}

// ---------------------------------------------------------------------------
// Kernel 3: mamba1 over each row of h (L=256, di=2, dt_rank=1, N=16) + h.
// 8 rows per 256-thread block (512 blocks).  32 lanes/row.
// Phase 0 sums the 4 h-partials (bias already in slice 0).
// ---------------------------------------------------------------------------
__global__ __launch_bounds__(256)
void mamba_res(const float* __restrict__ hp, float* __restrict__ out,
               const float* __restrict__ in_w, const float* __restrict__ conv_w,
               const float* __restrict__ conv_b, const float* __restrict__ xproj,
               const float* __restrict__ dt_w, const float* __restrict__ dt_b,
               const float* __restrict__ A_log, const float* __restrict__ Dp,
               const float* __restrict__ out_w) {
    __shared__ float4 arrS4[8 * 256];           // 32 KB
    __shared__ float  smem2[8 * 256 * 2 + 64];  // 16.25 KB

    const int tid = threadIdx.x;
    const int r0 = blockIdx.x * 8;
    const int row  = tid >> 5;   // 0..7
    const int lane = tid & 31;
    const int d    = lane >> 4;
    const int n    = lane & 15;

    // phase 0: sum 4 h-partials for 8 rows (coalesced)
    {
        const float4* h0 = (const float4*)(hp + r0 * 256);
        float4* dst = (float4*)&smem2[0];
#pragma unroll
        for (int q = 0; q < 2; ++q) {
            const int i = tid + q * 256;
            float4 p0 = h0[i];
            float4 p1 = h0[i + 262144];
            float4 p2 = h0[i + 524288];
            float4 p3 = h0[i + 786432];
            dst[i] = make_float4(p0.x + p1.x + p2.x + p3.x,
                                 p0.y + p1.y + p2.y + p3.y,
                                 p0.z + p1.z + p2.z + p3.z,
                                 p0.w + p1.w + p2.w + p3.w);
        }
    }

    const float iw0 = in_w[0], iw1 = in_w[1], iw2 = in_w[2], iw3 = in_w[3];
    const float g00 = iw0 * conv_w[0], g01 = iw0 * conv_w[1];
    const float g02 = iw0 * conv_w[2], g03 = iw0 * conv_w[3];
    const float g10 = iw1 * conv_w[4], g11 = iw1 * conv_w[5];
    const float g12 = iw1 * conv_w[6], g13 = iw1 * conv_w[7];
    const float cb0 = conv_b[0], cb1 = conv_b[1];
    const float xp00 = xproj[0], xp01 = xproj[1];
    const float dtw0 = dt_w[0], dtw1 = dt_w[1];
    const float dtb0 = dt_b[0], dtb1 = dt_b[1];
    const float D0 = Dp[0], D1 = Dp[1];
    const float ow0 = out_w[0], ow1 = out_w[1];

    __syncthreads();

    // phase 1: per-t precompute; keep w0/w1/base in registers for phase 3
    float w0a[8], w1a[8], basea[8];
#pragma unroll
    for (int j = 0; j < 8; ++j) {
        const int t = lane + 32 * j;
        const float* u = &smem2[row * 256];
        const float u0 = u[t];
        const int i1 = (t >= 1) ? t - 1 : 0;
        const int i2 = (t >= 2) ? t - 2 : 0;
        const int i3 = (t >= 3) ? t - 3 : 0;
        float um1 = u[i1]; um1 = (t >= 1) ? um1 : 0.f;
        float um2 = u[i2]; um2 = (t >= 2) ? um2 : 0.f;
        float um3 = u[i3]; um3 = (t >= 3) ? um3 : 0.f;

        const float p0 = fmaf(g03, u0, fmaf(g02, um1, fmaf(g01, um2, fmaf(g00, um3, cb0))));
        const float p1 = fmaf(g13, u0, fmaf(g12, um1, fmaf(g11, um2, fmaf(g10, um3, cb1))));
        const float xc0 = silu_f(p0);
        const float xc1 = silu_f(p1);
        const float dbc0 = fmaf(xp01, xc1, xp00 * xc0);
        const float dt0 = softplus_f(fmaf(dbc0, dtw0, dtb0));
        const float dt1 = softplus_f(fmaf(dbc0, dtw1, dtb1));
        const float w0 = silu_f(u0 * iw2) * ow0;
        const float w1 = silu_f(u0 * iw3) * ow1;
        w0a[j] = w0;
        w1a[j] = w1;
        basea[j] = fmaf(xc1 * D1, w1, fmaf(xc0 * D0, w0, u0));
        arrS4[row * 256 + t] = make_float4(xc0, xc1, dt0, dt1);
    }
    __syncthreads();  // arrS ready; smem2 reused as Sbuf (+trash tail)

    // phase 2: sequential scan; lane owns state (d, n)
    const float a_dn = -__expf(A_log[d * 16 + n]);
    const float bn0 = xproj[(1 + n) * 2 + 0];
    const float bn1 = xproj[(1 + n) * 2 + 1];
    const float cn0 = xproj[(17 + n) * 2 + 0];
    const float cn1 = xproj[(17 + n) * 2 + 1];
    const bool is_writer = ((lane & 15) == 15);
    const int trash = 4096 + (tid & 63);
    float hstate = 0.f;

#pragma unroll 8
    for (int t = 0; t < 256; ++t) {
        const float4 P = arrS4[row * 256 + t];  // {xc0, xc1, dt0, dt1}
        const float dtd = d ? P.w : P.z;
        const float xcd = d ? P.y : P.x;
        const float bm = fmaf(bn1, P.y, bn0 * P.x);
        const float cm = fmaf(cn1, P.y, cn0 * P.x);
        const float dA = __expf(dtd * a_dn);
        hstate = fmaf(dA, hstate, dtd * xcd * bm);
        float s = hstate * cm;
        DPP_ADD(s, 0x111);  // row_shr:1
        DPP_ADD(s, 0x112);  // row_shr:2
        DPP_ADD(s, 0x114);  // row_shr:4
        DPP_ADD(s, 0x118);  // row_shr:8 -> lane15 of each 16-row has S_d
        const int addr = is_writer ? (((row * 256 + t) << 1) + d) : trash;
        smem2[addr] = s;    // unconditional: no exec-mask toggle
    }
    __syncthreads();

    // phase 3: y = base + w0*S0 + w1*S1, coalesced stores
    float* orow = out + (r0 + row) * 256;
#pragma unroll
    for (int j = 0; j < 8; ++j) {
        const int t = lane + 32 * j;
        const float2 S = *(const float2*)&smem2[((row * 256 + t) << 1)];
        orow[t] = fmaf(w1a[j], S.y, fmaf(w0a[j], S.x, basea[j]));
    }
}

// ---------------------------------------------------------------------------
extern "C" void kernel_launch(void* const* d_in, const int* in_sizes, int n_in,
                              void* d_out, int out_size, void* d_ws, size_t ws_size,
                              hipStream_t stream) {
    const float* x      = (const float*)d_in[0];
    const float* lin1_w = (const float*)d_in[1];
    const float* lin1_b = (const float*)d_in[2];
    const float* lin2_w = (const float*)d_in[3];
    const float* lin2_b = (const float*)d_in[4];
    const float* m1_in_w   = (const float*)d_in[5];
    const float* m1_conv_w = (const float*)d_in[6];
    const float* m1_conv_b = (const float*)d_in[7];
    const float* m1_xproj  = (const float*)d_in[8];
    const float* m1_dt_w   = (const float*)d_in[9];
    const float* m1_dt_b   = (const float*)d_in[10];
    const float* m1_A_log  = (const float*)d_in[11];
    const float* m1_D      = (const float*)d_in[12];
    const float* m1_out_w  = (const float*)d_in[13];
    // d_in[14..22] = m2_* params: x1 branch is exactly zero (see analysis)

    float* out   = (float*)d_out;
    float* wsf   = (float*)d_ws;
    float* W2T   = wsf;                 // 131072 floats
    float* b2    = wsf + 131072;        // 256 floats
    float* hpart = wsf + 131328;        // 4 * 1048576 floats

    w2t_full<<<136, 256, 0, stream>>>(lin2_w, lin1_w, lin1_b, lin2_b, W2T, b2);
    gemm_h<<<dim3(32, 4, 4), 256, 0, stream>>>(x, W2T, b2, hpart);
    mamba_res<<<512, 256, 0, stream>>>(hpart, out, m1_in_w, m1_conv_w, m1_conv_b,
                                       m1_xproj, m1_dt_w, m1_dt_b, m1_A_log,
                                       m1_D, m1_out_w);
}

// Round 10
// 169.497 us; speedup vs baseline: 1.0035x; 1.0035x over previous
//
#include <hip/hip_runtime.h>

// ---------------------------------------------------------------------------
//   x: (32, 512, 128) fp32 -> rows r = b*128 + c, 4096 rows
//   h[r][n2] = sum_l xt[r][l] * W2[n2][l] + b2[n2],  W2 = lin2_w @ lin1_w
//   out[r][t] = h[r][t] + mamba1(h[r][:])[t]        (x1 branch is exactly 0)
// 3 dispatches: w2t (W2T + b2) -> gemm_h (split-K4, bias in kz0) -> mamba.
// Mamba scan is LDS-pipe-bound: params packed as 4xfp16 (b64 reads).
// ---------------------------------------------------------------------------

__device__ __forceinline__ float rcp_f(float x) { return __builtin_amdgcn_rcpf(x); }
__device__ __forceinline__ float silu_f(float x) {
    return x * rcp_f(1.0f + __expf(-x));
}
__device__ __forceinline__ float softplus_f(float x) {
    return fmaxf(x, 0.0f) + __logf(1.0f + __expf(-fabsf(x)));
}

// fp16 pack/unpack helpers (RTE via _Float16 casts)
__device__ __forceinline__ unsigned f2_to_h2(float a, float b) {
    _Float16 ha = (_Float16)a, hb = (_Float16)b;
    unsigned short ua = __builtin_bit_cast(unsigned short, ha);
    unsigned short ub = __builtin_bit_cast(unsigned short, hb);
    return (unsigned)ua | ((unsigned)ub << 16);
}
__device__ __forceinline__ float h16_to_f(unsigned u) {
    unsigned short s = (unsigned short)u;
    _Float16 h = __builtin_bit_cast(_Float16, s);
    return (float)h;
}

// DPP row_shr add (rows of 16 lanes); bound_ctrl=1 -> out-of-row reads 0.
#define DPP_ADD(s, ctrl)                                                       \
    (s) += __int_as_float(__builtin_amdgcn_update_dpp(                         \
        0, __float_as_int(s), (ctrl), 0xf, 0xf, true))

// ---------------------------------------------------------------------------
// Kernel 1: W2T[l*256+n2] = sum_n1 lin2[n2][n1]*lin1[n1][l]  (blocks 0..127)
//           b2 = lin2_w@lin1_b + lin2_b                      (blocks 128..135)
// ---------------------------------------------------------------------------
__global__ __launch_bounds__(256)
void w2t_full(const float* __restrict__ lin2_w, const float* __restrict__ lin1_w,
              const float* __restrict__ lin1_b, const float* __restrict__ lin2_b,
              float* __restrict__ W2T, float* __restrict__ b2) {
    __shared__ float As[64][34];
    __shared__ float Bs[64][36];
    const int bid = blockIdx.x;
    const int tid = threadIdx.x;
    if (bid >= 128) {
        __shared__ float red[8][33];
        const int np = tid & 31;
        const int ks = tid >> 5;
        const int n = (bid - 128) * 32 + np;
        float acc = 0.f;
#pragma unroll 16
        for (int k = ks * 64; k < ks * 64 + 64; k += 4) {
            float4 w  = *(const float4*)&lin2_w[n * 512 + k];
            float4 bb = *(const float4*)&lin1_b[k];
            acc += w.x * bb.x + w.y * bb.y + w.z * bb.z + w.w * bb.w;
        }
        red[ks][np] = acc;
        __syncthreads();
        if (ks == 0) {
            float s = red[0][np] + red[1][np] + red[2][np] + red[3][np] +
                      red[4][np] + red[5][np] + red[6][np] + red[7][np];
            b2[n] = s + lin2_b[n];
        }
        return;
    }
    const int m0 = (bid & 7) * 32;           // n2 tile
    const int n0 = ((bid >> 3) & 15) * 32;   // l tile
    const int tr = tid & 15;
    const int tc = tid >> 4;
    const int ma  = tid >> 3;
    const int kqa = tid & 7;
    const int kb  = tid >> 2;
    const int nqb = tid & 3;
    float acc00 = 0.f, acc01 = 0.f, acc10 = 0.f, acc11 = 0.f;

    for (int k0 = 0; k0 < 512; k0 += 64) {
        float4 a0 = *(const float4*)&lin2_w[(m0 + ma) * 512 + k0 + kqa * 8];
        float4 a1 = *(const float4*)&lin2_w[(m0 + ma) * 512 + k0 + kqa * 8 + 4];
        As[kqa * 8 + 0][ma] = a0.x;
        As[kqa * 8 + 1][ma] = a0.y;
        As[kqa * 8 + 2][ma] = a0.z;
        As[kqa * 8 + 3][ma] = a0.w;
        As[kqa * 8 + 4][ma] = a1.x;
        As[kqa * 8 + 5][ma] = a1.y;
        As[kqa * 8 + 6][ma] = a1.z;
        As[kqa * 8 + 7][ma] = a1.w;
        float4 b0 = *(const float4*)&lin1_w[(k0 + kb) * 512 + n0 + nqb * 8];
        float4 b1 = *(const float4*)&lin1_w[(k0 + kb) * 512 + n0 + nqb * 8 + 4];
        *(float4*)&Bs[kb][nqb * 8]     = b0;
        *(float4*)&Bs[kb][nqb * 8 + 4] = b1;
        __syncthreads();
#pragma unroll 16
        for (int kk = 0; kk < 64; ++kk) {
            float2 av = *(const float2*)&As[kk][tr * 2];
            float2 bv = *(const float2*)&Bs[kk][tc * 2];
            acc00 = fmaf(av.x, bv.x, acc00);
            acc01 = fmaf(av.x, bv.y, acc01);
            acc10 = fmaf(av.y, bv.x, acc10);
            acc11 = fmaf(av.y, bv.y, acc11);
        }
        __syncthreads();
    }
    const int m = m0 + tr * 2;
    const int nn = n0 + tc * 2;
    W2T[nn * 256 + m]           = acc00;
    W2T[nn * 256 + m + 1]       = acc10;
    W2T[(nn + 1) * 256 + m]     = acc01;
    W2T[(nn + 1) * 256 + m + 1] = acc11;
}

// ---------------------------------------------------------------------------
// Kernel 2: hpart[kz][r][n2] = sum_{l in kz*128..+128} xt[r][l]*W2T[l][n2]
// (+ b2 folded into kz==0).  BM=128, BN=64, BK=32, 8x4 micro, dbuf,
// grid (32,4,4) = 512 blocks (2/CU).
// ---------------------------------------------------------------------------
__global__ __launch_bounds__(256)
void gemm_h(const float* __restrict__ x, const float* __restrict__ W2T,
            const float* __restrict__ b2, float* __restrict__ hpart) {
    __shared__ float As[2][32][132];
    __shared__ float Bs[2][32][68];
    const int tid = threadIdx.x;
    const int b  = blockIdx.x;
    const int n0 = blockIdx.y * 64;
    const int kz = blockIdx.z;
    const int lbase = kz * 128;
    const int r0 = b * 128;
    const int ka = tid >> 3;
    const int c8 = tid & 7;
    const int tr = tid & 15;
    const int tc = tid >> 4;
    float acc[8][4] = {{0.f}};

    const float* xp = x + b * 65536;
    const float* wp = W2T + n0;

    float4 pa0, pa1, pa2, pa3, pb0, pb1;
#define LOADC(l0)                                                              \
    do {                                                                       \
        const float* xr = xp + ((l0) + ka) * 128;                              \
        pa0 = *(const float4*)&xr[c8 * 4];                                     \
        pa1 = *(const float4*)&xr[c8 * 4 + 32];                                \
        pa2 = *(const float4*)&xr[c8 * 4 + 64];                                \
        pa3 = *(const float4*)&xr[c8 * 4 + 96];                                \
        const float* wr = wp + ((l0) + ka) * 256;                              \
        pb0 = *(const float4*)&wr[c8 * 4];                                     \
        pb1 = *(const float4*)&wr[c8 * 4 + 32];                                \
    } while (0)
#define STOREC(buf)                                                            \
    do {                                                                       \
        *(float4*)&As[buf][ka][c8 * 4]      = pa0;                             \
        *(float4*)&As[buf][ka][c8 * 4 + 32] = pa1;                             \
        *(float4*)&As[buf][ka][c8 * 4 + 64] = pa2;                             \
        *(float4*)&As[buf][ka][c8 * 4 + 96] = pa3;                             \
        *(float4*)&Bs[buf][ka][c8 * 4]      = pb0;                             \
        *(float4*)&Bs[buf][ka][c8 * 4 + 32] = pb1;                             \
    } while (0)

    LOADC(lbase);
    STOREC(0);
    for (int c = 0; c < 4; ++c) {
        __syncthreads();
        const int cur = c & 1;
        if (c < 3) LOADC(lbase + (c + 1) * 32);
#pragma unroll
        for (int kk = 0; kk < 32; ++kk) {
            float4 av0 = *(const float4*)&As[cur][kk][tr * 4];
            float4 av1 = *(const float4*)&As[cur][kk][64 + tr * 4];
            float4 bv  = *(const float4*)&Bs[cur][kk][tc * 4];
            const float am[8] = {av0.x, av0.y, av0.z, av0.w,
                                 av1.x, av1.y, av1.z, av1.w};
#pragma unroll
            for (int i = 0; i < 8; ++i) {
                acc[i][0] = fmaf(am[i], bv.x, acc[i][0]);
                acc[i][1] = fmaf(am[i], bv.y, acc[i][1]);
                acc[i][2] = fmaf(am[i], bv.z, acc[i][2]);
                acc[i][3] = fmaf(am[i], bv.w, acc[i][3]);
            }
        }
        if (c < 3) STOREC(cur ^ 1);
    }
#undef LOADC
#undef STOREC
    float4 bias = make_float4(0.f, 0.f, 0.f, 0.f);
    if (kz == 0) bias = *(const float4*)&b2[n0 + tc * 4];
    float* dst = hpart + kz * 1048576;
#pragma unroll
    for (int i = 0; i < 8; ++i) {
        const int rr = r0 + ((i < 4) ? (tr * 4 + i) : (64 + tr * 4 + i - 4));
        float4 v = make_float4(acc[i][0] + bias.x, acc[i][1] + bias.y,
                               acc[i][2] + bias.z, acc[i][3] + bias.w);
        *(float4*)&dst[rr * 256 + n0 + tc * 4] = v;
    }
}

// ---------------------------------------------------------------------------
// Kernel 3: mamba1 over each row of h (L=256, di=2, dt_rank=1, N=16) + h.
// 8 rows per 256-thread block (512 blocks, 2/CU).  32 lanes/row.
// Scan is LDS-pipe-bound: per-t params packed 4xfp16 -> ds_read_b64 (6 cyc)
// instead of b128 (12); unpack via v_cvt_f32_f16 (VALU has slack).
// ---------------------------------------------------------------------------
__global__ __launch_bounds__(256)
void mamba_res(const float* __restrict__ hp, float* __restrict__ out,
               const float* __restrict__ in_w, const float* __restrict__ conv_w,
               const float* __restrict__ conv_b, const float* __restrict__ xproj,
               const float* __restrict__ dt_w, const float* __restrict__ dt_b,
               const float* __restrict__ A_log, const float* __restrict__ Dp,
               const float* __restrict__ out_w) {
    __shared__ uint2 arrP[8 * 256];             // 16 KB: {h2(xc0,xc1), h2(dt0,dt1)}
    __shared__ float smem2[8 * 256 * 2 + 64];   // 16.25 KB: ubuf then Sbuf+trash

    const int tid = threadIdx.x;
    const int r0 = blockIdx.x * 8;
    const int row  = tid >> 5;   // 0..7
    const int lane = tid & 31;
    const int d    = lane >> 4;
    const int n    = lane & 15;

    // phase 0: sum 4 h-partials for 8 rows (coalesced)
    {
        const float4* h0 = (const float4*)(hp + r0 * 256);
        float4* dst = (float4*)&smem2[0];
#pragma unroll
        for (int q = 0; q < 2; ++q) {
            const int i = tid + q * 256;
            float4 p0 = h0[i];
            float4 p1 = h0[i + 262144];
            float4 p2 = h0[i + 524288];
            float4 p3 = h0[i + 786432];
            dst[i] = make_float4(p0.x + p1.x + p2.x + p3.x,
                                 p0.y + p1.y + p2.y + p3.y,
                                 p0.z + p1.z + p2.z + p3.z,
                                 p0.w + p1.w + p2.w + p3.w);
        }
    }

    const float iw0 = in_w[0], iw1 = in_w[1], iw2 = in_w[2], iw3 = in_w[3];
    const float g00 = iw0 * conv_w[0], g01 = iw0 * conv_w[1];
    const float g02 = iw0 * conv_w[2], g03 = iw0 * conv_w[3];
    const float g10 = iw1 * conv_w[4], g11 = iw1 * conv_w[5];
    const float g12 = iw1 * conv_w[6], g13 = iw1 * conv_w[7];
    const float cb0 = conv_b[0], cb1 = conv_b[1];
    const float xp00 = xproj[0], xp01 = xproj[1];
    const float dtw0 = dt_w[0], dtw1 = dt_w[1];
    const float dtb0 = dt_b[0], dtb1 = dt_b[1];
    const float D0 = Dp[0], D1 = Dp[1];
    const float ow0 = out_w[0], ow1 = out_w[1];

    __syncthreads();

    // phase 1: per-t precompute; pack params to 4xfp16; keep w/base in regs
    float w0a[8], w1a[8], basea[8];
#pragma unroll
    for (int j = 0; j < 8; ++j) {
        const int t = lane + 32 * j;
        const float* u = &smem2[row * 256];
        const float u0 = u[t];
        const int i1 = (t >= 1) ? t - 1 : 0;
        const int i2 = (t >= 2) ? t - 2 : 0;
        const int i3 = (t >= 3) ? t - 3 : 0;
        float um1 = u[i1]; um1 = (t >= 1) ? um1 : 0.f;
        float um2 = u[i2]; um2 = (t >= 2) ? um2 : 0.f;
        float um3 = u[i3]; um3 = (t >= 3) ? um3 : 0.f;

        const float p0 = fmaf(g03, u0, fmaf(g02, um1, fmaf(g01, um2, fmaf(g00, um3, cb0))));
        const float p1 = fmaf(g13, u0, fmaf(g12, um1, fmaf(g11, um2, fmaf(g10, um3, cb1))));
        const float xc0 = silu_f(p0);
        const float xc1 = silu_f(p1);
        const float dbc0 = fmaf(xp01, xc1, xp00 * xc0);
        const float dt0 = softplus_f(fmaf(dbc0, dtw0, dtb0));
        const float dt1 = softplus_f(fmaf(dbc0, dtw1, dtb1));
        const float w0 = silu_f(u0 * iw2) * ow0;
        const float w1 = silu_f(u0 * iw3) * ow1;
        w0a[j] = w0;
        w1a[j] = w1;
        basea[j] = fmaf(xc1 * D1, w1, fmaf(xc0 * D0, w0, u0));
        arrP[row * 256 + t] = make_uint2(f2_to_h2(xc0, xc1), f2_to_h2(dt0, dt1));
    }
    __syncthreads();  // arrP ready; smem2 reused as Sbuf (+trash tail)

    // phase 2: sequential scan; lane owns state (d, n)
    const float a_dn = -__expf(A_log[d * 16 + n]);
    const float bn0 = xproj[(1 + n) * 2 + 0];
    const float bn1 = xproj[(1 + n) * 2 + 1];
    const float cn0 = xproj[(17 + n) * 2 + 0];
    const float cn1 = xproj[(17 + n) * 2 + 1];
    const bool is_writer = ((lane & 15) == 15);
    const int dsh = d * 16;  // fp16 select shift for dt_d
    int addr = is_writer ? (row * 512 + d) : (4096 + (tid & 63));
    const int astep = is_writer ? 2 : 0;
    float hstate = 0.f;

#pragma unroll 8
    for (int t = 0; t < 256; ++t) {
        const uint2 P = arrP[row * 256 + t];  // {h2(xc0,xc1), h2(dt0,dt1)}
        const float xc0 = h16_to_f(P.x);
        const float xc1 = h16_to_f(P.x >> 16);
        const float dtd = h16_to_f(P.y >> dsh);
        const float xcd = d ? xc1 : xc0;
        const float bm = fmaf(bn1, xc1, bn0 * xc0);
        const float cm = fmaf(cn1, xc1, cn0 * xc0);
        const float dA = __expf(dtd * a_dn);
        hstate = fmaf(dA, hstate, dtd * xcd * bm);
        float s = hstate * cm;
        DPP_ADD(s, 0x111);  // row_shr:1
        DPP_ADD(s, 0x112);  // row_shr:2
        DPP_ADD(s, 0x114);  // row_shr:4
        DPP_ADD(s, 0x118);  // row_shr:8 -> lane15 of each 16-row has S_d
        smem2[addr] = s;    // unconditional (trash slot for non-writers)
        addr += astep;
    }
    __syncthreads();

    // phase 3: y = base + w0*S0 + w1*S1, coalesced stores
    float* orow = out + (r0 + row) * 256;
#pragma unroll
    for (int j = 0; j < 8; ++j) {
        const int t = lane + 32 * j;
        const float2 S = *(const float2*)&smem2[((row * 256 + t) << 1)];
        orow[t] = fmaf(w1a[j], S.y, fmaf(w0a[j], S.x, basea[j]));
    }
}

// ---------------------------------------------------------------------------
extern "C" void kernel_launch(void* const* d_in, const int* in_sizes, int n_in,
                              void* d_out, int out_size, void* d_ws, size_t ws_size,
                              hipStream_t stream) {
    const float* x      = (const float*)d_in[0];
    const float* lin1_w = (const float*)d_in[1];
    const float* lin1_b = (const float*)d_in[2];
    const float* lin2_w = (const float*)d_in[3];
    const float* lin2_b = (const float*)d_in[4];
    const float* m1_in_w   = (const float*)d_in[5];
    const float* m1_conv_w = (const float*)d_in[6];
    const float* m1_conv_b = (const float*)d_in[7];
    const float* m1_xproj  = (const float*)d_in[8];
    const float* m1_dt_w   = (const float*)d_in[9];
    const float* m1_dt_b   = (const float*)d_in[10];
    const float* m1_A_log  = (const float*)d_in[11];
    const float* m1_D      = (const float*)d_in[12];
    const float* m1_out_w  = (const float*)d_in[13];
    // d_in[14..22] = m2_* params: x1 branch is exactly zero (see analysis)

    float* out   = (float*)d_out;
    float* wsf   = (float*)d_ws;
    float* W2T   = wsf;                 // 131072 floats
    float* b2    = wsf + 131072;        // 256 floats
    float* hpart = wsf + 131328;        // 4 * 1048576 floats

    w2t_full<<<136, 256, 0, stream>>>(lin2_w, lin1_w, lin1_b, lin2_b, W2T, b2);
    gemm_h<<<dim3(32, 4, 4), 256, 0, stream>>>(x, W2T, b2, hpart);
    mamba_res<<<512, 256, 0, stream>>>(hpart, out, m1_in_w, m1_conv_w, m1_conv_b,
                                       m1_xproj, m1_dt_w, m1_dt_b, m1_A_log,
                                       m1_D, m1_out_w);
}

// Round 11
// 162.983 us; speedup vs baseline: 1.0436x; 1.0400x over previous
//
#include <hip/hip_runtime.h>

// ---------------------------------------------------------------------------
//   x: (32, 512, 128) fp32 -> rows r = b*128 + c, 4096 rows
//   h[r][n2] = sum_l xt[r][l] * W2[n2][l] + b2[n2],  W2 = lin2_w @ lin1_w
//   out[r][t] = h[r][t] + mamba1(h[r][:])[t]        (x1 branch is exactly 0)
// 4 dispatches (empirically fastest mix, R6 structure):
//   w2t_part (split-K4, 512 blk) -> w2t_fix -> gemm_h (split-K2, 512 blk)
//   -> mamba (8 rows/block, fp16-packed scan params, DPP reduce)
// ---------------------------------------------------------------------------

__device__ __forceinline__ float rcp_f(float x) { return __builtin_amdgcn_rcpf(x); }
__device__ __forceinline__ float silu_f(float x) {
    return x * rcp_f(1.0f + __expf(-x));
}
__device__ __forceinline__ float softplus_f(float x) {
    return fmaxf(x, 0.0f) + __logf(1.0f + __expf(-fabsf(x)));
}

__device__ __forceinline__ unsigned f2_to_h2(float a, float b) {
    _Float16 ha = (_Float16)a, hb = (_Float16)b;
    unsigned short ua = __builtin_bit_cast(unsigned short, ha);
    unsigned short ub = __builtin_bit_cast(unsigned short, hb);
    return (unsigned)ua | ((unsigned)ub << 16);
}
__device__ __forceinline__ float h16_to_f(unsigned u) {
    unsigned short s = (unsigned short)u;
    _Float16 h = __builtin_bit_cast(_Float16, s);
    return (float)h;
}

// DPP row_shr add (rows of 16 lanes); bound_ctrl=1 -> out-of-row reads 0.
#define DPP_ADD(s, ctrl)                                                       \
    (s) += __int_as_float(__builtin_amdgcn_update_dpp(                         \
        0, __float_as_int(s), (ctrl), 0xf, 0xf, true))

// ---------------------------------------------------------------------------
// Kernel 1: split-K partials of W2T[l*256+n2] = sum_n1 lin2[n2][n1]*lin1[n1][l]
// grid (8,16,4): bz = k-chunk of 128. 512 blocks (full chip).
// ---------------------------------------------------------------------------
__global__ __launch_bounds__(256)
void gemm_w2t_part(const float* __restrict__ A,   // lin2_w (256,512) [m][k]
                   const float* __restrict__ B,   // lin1_w (512,512) [k][n]
                   float* __restrict__ parts) {
    __shared__ float As[64][34];
    __shared__ float Bs[64][36];
    const int tid = threadIdx.x;
    const int m0 = blockIdx.x * 32;
    const int n0 = blockIdx.y * 32;
    const int kbase = blockIdx.z * 128;
    const int tr = tid & 15;
    const int tc = tid >> 4;
    const int ma  = tid >> 3;
    const int kqa = tid & 7;
    const int kb  = tid >> 2;
    const int nqb = tid & 3;
    float acc00 = 0.f, acc01 = 0.f, acc10 = 0.f, acc11 = 0.f;

    for (int k0 = kbase; k0 < kbase + 128; k0 += 64) {
        float4 a0 = *(const float4*)&A[(m0 + ma) * 512 + k0 + kqa * 8];
        float4 a1 = *(const float4*)&A[(m0 + ma) * 512 + k0 + kqa * 8 + 4];
        As[kqa * 8 + 0][ma] = a0.x;
        As[kqa * 8 + 1][ma] = a0.y;
        As[kqa * 8 + 2][ma] = a0.z;
        As[kqa * 8 + 3][ma] = a0.w;
        As[kqa * 8 + 4][ma] = a1.x;
        As[kqa * 8 + 5][ma] = a1.y;
        As[kqa * 8 + 6][ma] = a1.z;
        As[kqa * 8 + 7][ma] = a1.w;
        float4 b0 = *(const float4*)&B[(k0 + kb) * 512 + n0 + nqb * 8];
        float4 b1 = *(const float4*)&B[(k0 + kb) * 512 + n0 + nqb * 8 + 4];
        *(float4*)&Bs[kb][nqb * 8]     = b0;
        *(float4*)&Bs[kb][nqb * 8 + 4] = b1;
        __syncthreads();
#pragma unroll 16
        for (int kk = 0; kk < 64; ++kk) {
            float2 av = *(const float2*)&As[kk][tr * 2];
            float2 bv = *(const float2*)&Bs[kk][tc * 2];
            acc00 = fmaf(av.x, bv.x, acc00);
            acc01 = fmaf(av.x, bv.y, acc01);
            acc10 = fmaf(av.y, bv.x, acc10);
            acc11 = fmaf(av.y, bv.y, acc11);
        }
        __syncthreads();
    }
    float* dst = parts + blockIdx.z * 131072;
    const int m = m0 + tr * 2;
    const int nn = n0 + tc * 2;
    dst[nn * 256 + m]           = acc00;
    dst[nn * 256 + m + 1]       = acc10;
    dst[(nn + 1) * 256 + m]     = acc01;
    dst[(nn + 1) * 256 + m + 1] = acc11;
}

// ---------------------------------------------------------------------------
// Kernel 2: W2T = sum of 4 partials (blocks 0..127) and
//           b2 = lin2_w@lin1_b + lin2_b (blocks 128..135).
// ---------------------------------------------------------------------------
__global__ __launch_bounds__(256)
void w2t_fix(const float* __restrict__ parts, const float* __restrict__ lin2_w,
             const float* __restrict__ lin1_b, const float* __restrict__ lin2_b,
             float* __restrict__ W2T, float* __restrict__ b2) {
    __shared__ float red[8][33];
    const int bid = blockIdx.x;
    const int tid = threadIdx.x;
    if (bid < 128) {
        const int i = bid * 256 + tid;  // float4 index, 32768 total
        const float4* p = (const float4*)parts;
        float4 s0 = p[i];
        float4 s1 = p[i + 32768];
        float4 s2 = p[i + 65536];
        float4 s3 = p[i + 98304];
        float4 s = make_float4(s0.x + s1.x + s2.x + s3.x,
                               s0.y + s1.y + s2.y + s3.y,
                               s0.z + s1.z + s2.z + s3.z,
                               s0.w + s1.w + s2.w + s3.w);
        ((float4*)W2T)[i] = s;
    } else {
        const int np = tid & 31;
        const int ks = tid >> 5;
        const int n = (bid - 128) * 32 + np;
        float acc = 0.f;
#pragma unroll 16
        for (int k = ks * 64; k < ks * 64 + 64; k += 4) {
            float4 w  = *(const float4*)&lin2_w[n * 512 + k];
            float4 bb = *(const float4*)&lin1_b[k];
            acc += w.x * bb.x + w.y * bb.y + w.z * bb.z + w.w * bb.w;
        }
        red[ks][np] = acc;
        __syncthreads();
        if (ks == 0) {
            float s = red[0][np] + red[1][np] + red[2][np] + red[3][np] +
                      red[4][np] + red[5][np] + red[6][np] + red[7][np];
            b2[n] = s + lin2_b[n];
        }
    }
}

// ---------------------------------------------------------------------------
// Kernel 3: hpart[kz][r][n2] = sum_{l in kz*256..+256} xt[r][l]*W2T[l][n2]
// (+ b2 folded into kz==0).  BM=BN=64, BK=32, 4x4 micro, double-buffered,
// grid (64, 4, 2) = 512 blocks (2/CU, conflict-free LDS reads).
// ---------------------------------------------------------------------------
__global__ __launch_bounds__(256)
void gemm_h(const float* __restrict__ x, const float* __restrict__ W2T,
            const float* __restrict__ b2, float* __restrict__ hpart) {
    __shared__ float As[2][32][68];
    __shared__ float Bs[2][32][68];
    const int tid = threadIdx.x;
    const int bx = blockIdx.x;       // r tile of 64
    const int n0 = blockIdx.y * 64;  // n2 tile
    const int kz = blockIdx.z;       // l-chunk of 256
    const int lbase = kz * 256;
    const int b  = bx >> 1;
    const int c0 = (bx & 1) * 64;
    const int r0 = bx * 64;
    const int cc = tid & 15;
    const int kr = tid >> 4;
    const int tr = tid & 15;
    const int tc = tid >> 4;
    float acc[4][4] = {{0.f}};

    const float* xp = x + b * 65536 + c0 + cc * 4;
    const float* wp = W2T + n0 + cc * 4;

    float4 pa0, pa1, pb0, pb1;
#define LOADC(l0)                                                              \
    do {                                                                       \
        pa0 = *(const float4*)&xp[((l0) + kr) * 128];                          \
        pa1 = *(const float4*)&xp[((l0) + kr + 16) * 128];                     \
        pb0 = *(const float4*)&wp[((l0) + kr) * 256];                          \
        pb1 = *(const float4*)&wp[((l0) + kr + 16) * 256];                     \
    } while (0)
#define STOREC(buf)                                                            \
    do {                                                                       \
        *(float4*)&As[buf][kr][cc * 4]      = pa0;                             \
        *(float4*)&As[buf][kr + 16][cc * 4] = pa1;                             \
        *(float4*)&Bs[buf][kr][cc * 4]      = pb0;                             \
        *(float4*)&Bs[buf][kr + 16][cc * 4] = pb1;                             \
    } while (0)

    LOADC(lbase);
    STOREC(0);
    for (int c = 0; c < 8; ++c) {
        __syncthreads();
        const int cur = c & 1;
        if (c < 7) LOADC(lbase + (c + 1) * 32);
#pragma unroll
        for (int kk = 0; kk < 32; ++kk) {
            float4 av = *(const float4*)&As[cur][kk][tr * 4];
            float4 bv = *(const float4*)&Bs[cur][kk][tc * 4];
            acc[0][0] = fmaf(av.x, bv.x, acc[0][0]);
            acc[0][1] = fmaf(av.x, bv.y, acc[0][1]);
            acc[0][2] = fmaf(av.x, bv.z, acc[0][2]);
            acc[0][3] = fmaf(av.x, bv.w, acc[0][3]);
            acc[1][0] = fmaf(av.y, bv.x, acc[1][0]);
            acc[1][1] = fmaf(av.y, bv.y, acc[1][1]);
            acc[1][2] = fmaf(av.y, bv.z, acc[1][2]);
            acc[1][3] = fmaf(av.y, bv.w, acc[1][3]);
            acc[2][0] = fmaf(av.z, bv.x, acc[2][0]);
            acc[2][1] = fmaf(av.z, bv.y, acc[2][1]);
            acc[2][2] = fmaf(av.z, bv.z, acc[2][2]);
            acc[2][3] = fmaf(av.z, bv.w, acc[2][3]);
            acc[3][0] = fmaf(av.w, bv.x, acc[3][0]);
            acc[3][1] = fmaf(av.w, bv.y, acc[3][1]);
            acc[3][2] = fmaf(av.w, bv.z, acc[3][2]);
            acc[3][3] = fmaf(av.w, bv.w, acc[3][3]);
        }
        if (c < 7) STOREC(cur ^ 1);
    }
#undef LOADC
#undef STOREC
    float4 bias = make_float4(0.f, 0.f, 0.f, 0.f);
    if (kz == 0) bias = *(const float4*)&b2[n0 + tc * 4];
    float* dst = hpart + kz * 1048576;
#pragma unroll
    for (int i = 0; i < 4; ++i) {
        float4 v = make_float4(acc[i][0] + bias.x, acc[i][1] + bias.y,
                               acc[i][2] + bias.z, acc[i][3] + bias.w);
        *(float4*)&dst[(r0 + tr * 4 + i) * 256 + n0 + tc * 4] = v;
    }
}

// ---------------------------------------------------------------------------
// Kernel 4: mamba1 over each row of h (L=256, di=2, dt_rank=1, N=16) + h.
// 8 rows per 256-thread block (512 blocks, 2/CU).  32 lanes/row.
// Phase 0 sums the 2 h-partials.  Scan params packed 4xfp16 (b64 reads);
// unconditional ds_write with cndmask'd address (no exec toggle).
// ---------------------------------------------------------------------------
__global__ __launch_bounds__(256)
void mamba_res(const float* __restrict__ hp, float* __restrict__ out,
               const float* __restrict__ in_w, const float* __restrict__ conv_w,
               const float* __restrict__ conv_b, const float* __restrict__ xproj,
               const float* __restrict__ dt_w, const float* __restrict__ dt_b,
               const float* __restrict__ A_log, const float* __restrict__ Dp,
               const float* __restrict__ out_w) {
    __shared__ uint2 arrP[8 * 256];             // 16 KB
    __shared__ float smem2[8 * 256 * 2 + 64];   // 16.25 KB

    const int tid = threadIdx.x;
    const int r0 = blockIdx.x * 8;
    const int row  = tid >> 5;   // 0..7
    const int lane = tid & 31;
    const int d    = lane >> 4;
    const int n    = lane & 15;

    // phase 0: sum 2 h-partials for 8 rows (coalesced)
    {
        const float4* h0 = (const float4*)(hp + r0 * 256);
        float4* dst = (float4*)&smem2[0];
#pragma unroll
        for (int q = 0; q < 2; ++q) {
            const int i = tid + q * 256;
            float4 p0 = h0[i];
            float4 p1 = h0[i + 262144];
            dst[i] = make_float4(p0.x + p1.x, p0.y + p1.y,
                                 p0.z + p1.z, p0.w + p1.w);
        }
    }

    const float iw0 = in_w[0], iw1 = in_w[1], iw2 = in_w[2], iw3 = in_w[3];
    const float g00 = iw0 * conv_w[0], g01 = iw0 * conv_w[1];
    const float g02 = iw0 * conv_w[2], g03 = iw0 * conv_w[3];
    const float g10 = iw1 * conv_w[4], g11 = iw1 * conv_w[5];
    const float g12 = iw1 * conv_w[6], g13 = iw1 * conv_w[7];
    const float cb0 = conv_b[0], cb1 = conv_b[1];
    const float xp00 = xproj[0], xp01 = xproj[1];
    const float dtw0 = dt_w[0], dtw1 = dt_w[1];
    const float dtb0 = dt_b[0], dtb1 = dt_b[1];
    const float D0 = Dp[0], D1 = Dp[1];
    const float ow0 = out_w[0], ow1 = out_w[1];

    __syncthreads();

    // phase 1: per-t precompute; pack params to 4xfp16; keep w/base in regs
    float w0a[8], w1a[8], basea[8];
#pragma unroll
    for (int j = 0; j < 8; ++j) {
        const int t = lane + 32 * j;
        const float* u = &smem2[row * 256];
        const float u0 = u[t];
        const int i1 = (t >= 1) ? t - 1 : 0;
        const int i2 = (t >= 2) ? t - 2 : 0;
        const int i3 = (t >= 3) ? t - 3 : 0;
        float um1 = u[i1]; um1 = (t >= 1) ? um1 : 0.f;
        float um2 = u[i2]; um2 = (t >= 2) ? um2 : 0.f;
        float um3 = u[i3]; um3 = (t >= 3) ? um3 : 0.f;

        const float p0 = fmaf(g03, u0, fmaf(g02, um1, fmaf(g01, um2, fmaf(g00, um3, cb0))));
        const float p1 = fmaf(g13, u0, fmaf(g12, um1, fmaf(g11, um2, fmaf(g10, um3, cb1))));
        const float xc0 = silu_f(p0);
        const float xc1 = silu_f(p1);
        const float dbc0 = fmaf(xp01, xc1, xp00 * xc0);
        const float dt0 = softplus_f(fmaf(dbc0, dtw0, dtb0));
        const float dt1 = softplus_f(fmaf(dbc0, dtw1, dtb1));
        const float w0 = silu_f(u0 * iw2) * ow0;
        const float w1 = silu_f(u0 * iw3) * ow1;
        w0a[j] = w0;
        w1a[j] = w1;
        basea[j] = fmaf(xc1 * D1, w1, fmaf(xc0 * D0, w0, u0));
        arrP[row * 256 + t] = make_uint2(f2_to_h2(xc0, xc1), f2_to_h2(dt0, dt1));
    }
    __syncthreads();  // arrP ready; smem2 reused as Sbuf (+trash tail)

    // phase 2: sequential scan; lane owns state (d, n)
    const float a_dn = -__expf(A_log[d * 16 + n]);
    const float bn0 = xproj[(1 + n) * 2 + 0];
    const float bn1 = xproj[(1 + n) * 2 + 1];
    const float cn0 = xproj[(17 + n) * 2 + 0];
    const float cn1 = xproj[(17 + n) * 2 + 1];
    const bool is_writer = ((lane & 15) == 15);
    const int dsh = d * 16;  // fp16 select shift for dt_d
    int addr = is_writer ? (row * 512 + d) : (4096 + (tid & 63));
    const int astep = is_writer ? 2 : 0;
    float hstate = 0.f;

#pragma unroll 8
    for (int t = 0; t < 256; ++t) {
        const uint2 P = arrP[row * 256 + t];  // {h2(xc0,xc1), h2(dt0,dt1)}
        const float xc0 = h16_to_f(P.x);
        const float xc1 = h16_to_f(P.x >> 16);
        const float dtd = h16_to_f(P.y >> dsh);
        const float xcd = d ? xc1 : xc0;
        const float bm = fmaf(bn1, xc1, bn0 * xc0);
        const float cm = fmaf(cn1, xc1, cn0 * xc0);
        const float dA = __expf(dtd * a_dn);
        hstate = fmaf(dA, hstate, dtd * xcd * bm);
        float s = hstate * cm;
        DPP_ADD(s, 0x111);  // row_shr:1
        DPP_ADD(s, 0x112);  // row_shr:2
        DPP_ADD(s, 0x114);  // row_shr:4
        DPP_ADD(s, 0x118);  // row_shr:8 -> lane15 of each 16-row has S_d
        smem2[addr] = s;    // unconditional (trash slot for non-writers)
        addr += astep;
    }
    __syncthreads();

    // phase 3: y = base + w0*S0 + w1*S1, coalesced stores
    float* orow = out + (r0 + row) * 256;
#pragma unroll
    for (int j = 0; j < 8; ++j) {
        const int t = lane + 32 * j;
        const float2 S = *(const float2*)&smem2[((row * 256 + t) << 1)];
        orow[t] = fmaf(w1a[j], S.y, fmaf(w0a[j], S.x, basea[j]));
    }
}

// ---------------------------------------------------------------------------
extern "C" void kernel_launch(void* const* d_in, const int* in_sizes, int n_in,
                              void* d_out, int out_size, void* d_ws, size_t ws_size,
                              hipStream_t stream) {
    const float* x      = (const float*)d_in[0];
    const float* lin1_w = (const float*)d_in[1];
    const float* lin1_b = (const float*)d_in[2];
    const float* lin2_w = (const float*)d_in[3];
    const float* lin2_b = (const float*)d_in[4];
    const float* m1_in_w   = (const float*)d_in[5];
    const float* m1_conv_w = (const float*)d_in[6];
    const float* m1_conv_b = (const float*)d_in[7];
    const float* m1_xproj  = (const float*)d_in[8];
    const float* m1_dt_w   = (const float*)d_in[9];
    const float* m1_dt_b   = (const float*)d_in[10];
    const float* m1_A_log  = (const float*)d_in[11];
    const float* m1_D      = (const float*)d_in[12];
    const float* m1_out_w  = (const float*)d_in[13];
    // d_in[14..22] = m2_* params: x1 branch is exactly zero (see analysis)

    float* out   = (float*)d_out;
    float* wsf   = (float*)d_ws;
    float* parts = wsf;                 // 524288 floats
    float* W2T   = wsf + 524288;        // 131072 floats
    float* b2    = wsf + 655360;        // 256 floats
    float* hpart = wsf + 655616;        // 2 * 1048576 floats

    gemm_w2t_part<<<dim3(8, 16, 4), 256, 0, stream>>>(lin2_w, lin1_w, parts);
    w2t_fix<<<136, 256, 0, stream>>>(parts, lin2_w, lin1_b, lin2_b, W2T, b2);
    gemm_h<<<dim3(64, 4, 2), 256, 0, stream>>>(x, W2T, b2, hpart);
    mamba_res<<<512, 256, 0, stream>>>(hpart, out, m1_in_w, m1_conv_w, m1_conv_b,
                                       m1_xproj, m1_dt_w, m1_dt_b, m1_A_log,
                                       m1_D, m1_out_w);
}